// Round 4
// baseline (108.468 us; speedup 1.0000x reference)
//
#include <hip/hip_runtime.h>

// NEAT windowed-DAG forward, 2-lanes-per-element x 2-elements-per-lane.
//   values[0:16] = x; for i in 0..511: v = tanh(dot(values[i:i+16], w[i]) + b[i]) * r[i]
//   out = values[T-64:T]
//
// R10: cross-round model fit shows the invariant floor is the per-CU LDS
// pipe: every config had waves/CU x ds_reads/wave/node ~= 110-120 cyc/node
// (R6 2x5 b128, R7/R8 8x1.25, R9 4x2.5) and wall ~= DS-floor x 1.5. VALU
// issue per SIMD was never binding. Fix: halve DS traffic by halving
// waves/CU, recover parallelism as in-lane ILP: each lane-pair processes
// TWO batch elements (A,B) off the SAME weight registers. 512 waves =
// 2 waves/CU (block=128, grid=256). DS/CU/node ~54 cyc; issue ~60 cyc on
// 2 SIMDs; B's independent chain fills A's latency bubbles.
//
// u-domain (R8/R9 verified): carry u = sigmoid(-2z); staged weights
// W" = -2*kScale*w*rho_src, meta Bh = kScale*(b + sum_j w*rho)/2; inputs
// u=(1-x)/2; outputs o = r*(1-2u).
//
// LDS delivery byte-identical to R9: per 2-node group = 4 per-lane weight
// b128 + 1 meta b64, 4 rotating sets, depth-3 prefetch, exact counted
// s_waitcnt lgkmcnt(15).

typedef float v4f __attribute__((ext_vector_type(4)));
typedef float v2f __attribute__((ext_vector_type(2)));

constexpr int kNOut     = 64;
constexpr int kBatch    = 32768;
constexpr int kGStrideF = 48;                       // floats per 2-node group (192 B)
constexpr int kLdsFloats = (256 + 3) * kGStrideF;   // 256 groups + prefetch overrun pad
constexpr float kScale  = 2.8853900817779268f;      // 2*log2(e)

// quad_perm DPP through the builtin so the compiler handles hazard nops.
#define QPERM(X, CTRL) __int_as_float(__builtin_amdgcn_update_dpp(            \
    __float_as_int(X), __float_as_int(X), (CTRL), 0xF, 0xF, false))

// Issue the 5 ds_read for group S (nodes 2q,2q+1): per-lane weight halves
// of both nodes + meta b64 (BhA,BhB). Cursor a = group_base + 32*jl, so
// lane0 meta lands at byte 128 and lane1 at its replica at byte 160.
#define PREF(S) {                                                             \
    asm volatile(                                                             \
      "ds_read_b128 %0, %5 offset:0\n\t"                                      \
      "ds_read_b128 %1, %5 offset:16\n\t"                                     \
      "ds_read_b128 %2, %5 offset:64\n\t"                                     \
      "ds_read_b128 %3, %5 offset:80\n\t"                                     \
      "ds_read_b64  %4, %5 offset:128"                                        \
      : "=&v"(qa[S]), "=&v"(qb[S]), "=&v"(qc[S]), "=&v"(qd[S]), "=&v"(qm[S])  \
      : "v"(a));                                                              \
    a += kGStrideF * 4; }

// After PREF of group G+3, the 15 newer reads (groups G+1..G+3) may remain
// outstanding; in-order DS returns make lgkmcnt(15) == "set G landed".
#define WAITG(S)                                                              \
    asm volatile("s_waitcnt lgkmcnt(15)"                                      \
      : "+v"(qa[S]), "+v"(qb[S]), "+v"(qc[S]), "+v"(qd[S]), "+v"(qm[S]));

// One node, TWO elements (A,B) sharing the weight regs. A0..A7 / B0..B7 =
// each element's window half in age order (lane1's *7 = previous node's u,
// consumed by the LAST fma -> only serial-chain op). BH = B"/2 enters both
// lanes' fma init. Reduce: one dpp-add pair per element. Migration: lane0's
// vacated *0 pulls lane1's *0; lane1's *0 gets the new u.
#define NODE1(WLO, WHI, BH, A0,A1,A2,A3,A4,A5,A6,A7,                          \
                            B0,B1,B2,B3,B4,B5,B6,B7) {                        \
    float pA = fmaf((A0), (WLO).x, (BH));                                     \
    float pB = fmaf((B0), (WLO).x, (BH));                                     \
    pA = fmaf((A1), (WLO).y, pA);  pB = fmaf((B1), (WLO).y, pB);              \
    pA = fmaf((A2), (WLO).z, pA);  pB = fmaf((B2), (WLO).z, pB);              \
    pA = fmaf((A3), (WLO).w, pA);  pB = fmaf((B3), (WLO).w, pB);              \
    pA = fmaf((A4), (WHI).x, pA);  pB = fmaf((B4), (WHI).x, pB);              \
    pA = fmaf((A5), (WHI).y, pA);  pB = fmaf((B5), (WHI).y, pB);              \
    pA = fmaf((A6), (WHI).z, pA);  pB = fmaf((B6), (WHI).z, pB);              \
    pA = fmaf((A7), (WHI).w, pA);  pB = fmaf((B7), (WHI).w, pB);              \
    float sA = pA + QPERM(pA, 0xB1);        /* quad_perm:[1,0,3,2] */         \
    float sB = pB + QPERM(pB, 0xB1);                                          \
    float eA_ = __builtin_amdgcn_exp2f(sA);                                   \
    float eB_ = __builtin_amdgcn_exp2f(sB);                                   \
    float uA = __builtin_amdgcn_rcpf(eA_ + 1.0f);                             \
    float uB = __builtin_amdgcn_rcpf(eB_ + 1.0f);                             \
    float mA = QPERM((A0), 0xB1);           /* pull partner's *0 */           \
    float mB = QPERM((B0), 0xB1);                                             \
    (A0) = is_l1 ? uA : mA;                                                   \
    (B0) = is_l1 ? uB : mB; }

// 2-node group: prefetch group G+3, wait for group G, run both nodes.
#define GROUP(G, O0,O1,O2,O3,O4,O5,O6,O7, P0,P1,P2,P3,P4,P5,P6,P7) {          \
    PREF(((G) + 3) & 3)                                                       \
    WAITG((G) & 3)                                                            \
    NODE1(qa[(G) & 3], qb[(G) & 3], qm[(G) & 3].x,                            \
          rA##O0,rA##O1,rA##O2,rA##O3,rA##O4,rA##O5,rA##O6,rA##O7,            \
          rB##O0,rB##O1,rB##O2,rB##O3,rB##O4,rB##O5,rB##O6,rB##O7)            \
    NODE1(qc[(G) & 3], qd[(G) & 3], qm[(G) & 3].y,                            \
          rA##P0,rA##P1,rA##P2,rA##P3,rA##P4,rA##P5,rA##P6,rA##P7,            \
          rB##P0,rB##P1,rB##P2,rB##P3,rB##P4,rB##P5,rB##P6,rB##P7) }

__global__ __launch_bounds__(128) void neat_fwd(
    const float* __restrict__ x,      // [B, 16]
    const float* __restrict__ w,      // [512, 16]
    const float* __restrict__ bias,   // [512]
    const float* __restrict__ resp,   // [512]
    float* __restrict__ out)          // [B, 64]
{
    __shared__ alignas(16) float ldsw[kLdsFloats];
    __shared__ float rst[512];
    __shared__ float sums[512];       // per-node sum_j w_ij * rho_j (unscaled)

    const int t  = threadIdx.x;       // 0..127 (2 waves)
    const int jl = t & 1;             // lane within pair
    const bool is_l1 = (jl == 1);

    // ---- Stage: raw resp first ----
    #pragma unroll
    for (int k = 0; k < 4; ++k) rst[t + k * 128] = resp[t + k * 128];
    __syncthreads();

    // ---- Stage weights W" = -2*kScale*w*rho + per-node sums via DPP ----
    const float4* __restrict__ w4 = reinterpret_cast<const float4*>(w);
    #pragma unroll
    for (int k = 0; k < 16; ++k) {
        int i4 = t + k * 128;                 // [0, 2048) float4s of w
        float4 v = w4[i4];
        int n = i4 >> 2, k4 = i4 & 3;
        int s0 = n + 4 * k4;                  // global value idx of component .x
        float rho0 = (s0 + 0 < 16) ? 1.0f : rst[s0 - 16];
        float rho1 = (s0 + 1 < 16) ? 1.0f : rst[s0 - 15];
        float rho2 = (s0 + 2 < 16) ? 1.0f : rst[s0 - 14];
        float rho3 = (s0 + 3 < 16) ? 1.0f : rst[s0 - 13];
        float wr0 = v.x * rho0, wr1 = v.y * rho1,
              wr2 = v.z * rho2, wr3 = v.w * rho3;
        // quarter partial of sum_j w*rho; threads 4m..4m+3 hold the 4
        // quarters of node n -> quad DPP reduce.
        float ps = (wr0 + wr1) + (wr2 + wr3);
        ps += QPERM(ps, 0xB1);
        ps += QPERM(ps, 0x4E);
        if ((t & 3) == 0) sums[n] = ps;
        const float m2k = -2.0f * kScale;
        float4 sc = make_float4(wr0 * m2k, wr1 * m2k, wr2 * m2k, wr3 * m2k);
        *reinterpret_cast<float4*>(
            &ldsw[(n >> 1) * kGStrideF + (n & 1) * 16 + k4 * 4]) = sc;
    }
    __syncthreads();

    // meta: Bh = kScale*(b + sum w*rho)/2 per node, two replicas per group
    #pragma unroll
    for (int k = 0; k < 4; ++k) {
        int n = t + k * 128;
        float Bh = (bias[n] + sums[n]) * (kScale * 0.5f);
        int q = n >> 1, s = n & 1;
        ldsw[q * kGStrideF + 32 + s] = Bh;   // lane0's replica (byte 128)
        ldsw[q * kGStrideF + 40 + s] = Bh;   // lane1's replica (byte 160)
    }

    // ---- Per-thread state: window halves (u-encoded) for elements A,B ----
    const int eA = blockIdx.x * 128 + (t >> 1);     // batch element A
    const int eB = eA + 64;                         // batch element B
    const float4* __restrict__ x4 = reinterpret_cast<const float4*>(x);
    const float4 xa = x4[eA * 4 + 2 * jl], xb = x4[eA * 4 + 2 * jl + 1];
    const float4 xc = x4[eB * 4 + 2 * jl], xd = x4[eB * 4 + 2 * jl + 1];
    // u-encode inputs: u = (1 - x)/2  (exact affine; t = 1-2u recovers x)
    float rA0 = fmaf(-0.5f, xa.x, 0.5f), rA1 = fmaf(-0.5f, xa.y, 0.5f);
    float rA2 = fmaf(-0.5f, xa.z, 0.5f), rA3 = fmaf(-0.5f, xa.w, 0.5f);
    float rA4 = fmaf(-0.5f, xb.x, 0.5f), rA5 = fmaf(-0.5f, xb.y, 0.5f);
    float rA6 = fmaf(-0.5f, xb.z, 0.5f), rA7 = fmaf(-0.5f, xb.w, 0.5f);
    float rB0 = fmaf(-0.5f, xc.x, 0.5f), rB1 = fmaf(-0.5f, xc.y, 0.5f);
    float rB2 = fmaf(-0.5f, xc.z, 0.5f), rB3 = fmaf(-0.5f, xc.w, 0.5f);
    float rB4 = fmaf(-0.5f, xd.x, 0.5f), rB5 = fmaf(-0.5f, xd.y, 0.5f);
    float rB6 = fmaf(-0.5f, xd.z, 0.5f), rB7 = fmaf(-0.5f, xd.w, 0.5f);

    const float4* __restrict__ rr4 = reinterpret_cast<const float4*>(resp);
    float* __restrict__ opA = out + (size_t)eA * kNOut + jl * 8;
    float* __restrict__ opB = out + (size_t)eB * kNOut + jl * 8;

    __syncthreads();   // drains staging ds ops (compiler lgkmcnt(0))

    // DS byte cursor (+ lane's 32B weight-half offset folded in).
    unsigned int a = (unsigned int)(unsigned long long)(&ldsw[0])
                   + (unsigned int)(jl << 5);

    v4f qa[4], qb[4], qc[4], qd[4];
    v2f qm[4];
    PREF(0) PREF(1) PREF(2)     // groups 0,1,2 in flight

    #pragma unroll 1
    for (int g = 0; g < 32; ++g) {
        // 16 nodes = 8 groups; rotation start for node n is n&7.
        GROUP(0, 0,1,2,3,4,5,6,7,  1,2,3,4,5,6,7,0)
        GROUP(1, 2,3,4,5,6,7,0,1,  3,4,5,6,7,0,1,2)
        GROUP(2, 4,5,6,7,0,1,2,3,  5,6,7,0,1,2,3,4)
        GROUP(3, 6,7,0,1,2,3,4,5,  7,0,1,2,3,4,5,6)
        GROUP(4, 0,1,2,3,4,5,6,7,  1,2,3,4,5,6,7,0)
        GROUP(5, 2,3,4,5,6,7,0,1,  3,4,5,6,7,0,1,2)
        GROUP(6, 4,5,6,7,0,1,2,3,  5,6,7,0,1,2,3,4)
        GROUP(7, 6,7,0,1,2,3,4,5,  7,0,1,2,3,4,5,6)
        // After 16 nodes, lane jl's r*0..r*7 = u of nodes 16g+8jl+{0..7}.
        if (g >= 28) {
            int m = g - 28;
            const float4 ra = rr4[112 + 4 * m + 2 * jl];
            const float4 rb = rr4[112 + 4 * m + 2 * jl + 1];
            float4 oA0 = make_float4(fmaf(-2.0f, rA0, 1.0f) * ra.x,
                                     fmaf(-2.0f, rA1, 1.0f) * ra.y,
                                     fmaf(-2.0f, rA2, 1.0f) * ra.z,
                                     fmaf(-2.0f, rA3, 1.0f) * ra.w);
            float4 oA1 = make_float4(fmaf(-2.0f, rA4, 1.0f) * rb.x,
                                     fmaf(-2.0f, rA5, 1.0f) * rb.y,
                                     fmaf(-2.0f, rA6, 1.0f) * rb.z,
                                     fmaf(-2.0f, rA7, 1.0f) * rb.w);
            float4 oB0 = make_float4(fmaf(-2.0f, rB0, 1.0f) * ra.x,
                                     fmaf(-2.0f, rB1, 1.0f) * ra.y,
                                     fmaf(-2.0f, rB2, 1.0f) * ra.z,
                                     fmaf(-2.0f, rB3, 1.0f) * ra.w);
            float4 oB1 = make_float4(fmaf(-2.0f, rB4, 1.0f) * rb.x,
                                     fmaf(-2.0f, rB5, 1.0f) * rb.y,
                                     fmaf(-2.0f, rB6, 1.0f) * rb.z,
                                     fmaf(-2.0f, rB7, 1.0f) * rb.w);
            *reinterpret_cast<float4*>(opA + 16 * m)     = oA0;
            *reinterpret_cast<float4*>(opA + 16 * m + 4) = oA1;
            *reinterpret_cast<float4*>(opB + 16 * m)     = oB0;
            *reinterpret_cast<float4*>(opB + 16 * m + 4) = oB1;
        }
    }

    // Drain overrun prefetches (pad groups 256..258).
    asm volatile("s_waitcnt lgkmcnt(0)" ::: "memory");
}

extern "C" void kernel_launch(void* const* d_in, const int* in_sizes, int n_in,
                              void* d_out, int out_size, void* d_ws, size_t ws_size,
                              hipStream_t stream) {
    const float* x    = (const float*)d_in[0];
    const float* w    = (const float*)d_in[1];
    const float* bias = (const float*)d_in[2];
    const float* resp = (const float*)d_in[3];
    float* out = (float*)d_out;
    // in_sizes[4] (src_idx) encodes the fixed windowed topology; hardcoded above.
    dim3 block(128);
    dim3 grid(kBatch / 128);   // 256 blocks -> 1/CU, 2 waves/CU (2 SIMDs busy)
    hipLaunchKernelGGL(neat_fwd, grid, block, 0, stream, x, w, bias, resp, out);
}

// Round 5
// 89.634 us; speedup vs baseline: 1.2101x; 1.2101x over previous
//
#include <hip/hip_runtime.h>

// NEAT windowed-DAG forward, 2-lanes-per-element, u-domain, 4-hop chain.
//   values[0:16] = x; for i in 0..511: v = tanh(dot(values[i:i+16], w[i]) + b[i]) * r[i]
//   out = values[T-64:T]
//
// R11: cross-round fit (VALU ~4cyc/instr matches VALUBusy in R6-R10) shows a
// constant ~100-cyc/node stall at 1 wave/SIMD = the serial recurrence exposed
// in lockstep (R9 chain: rcp->cndmask->fma->dpp->add->exp2->add->rcp, 8 hops,
// DPP hazards + 2 trans ops). R10 (fewer waves, more ILP) regressed 285 -> DS
// traffic is NOT the floor. This round keeps R9's exact shape (1024 waves,
// 4/CU, 5-read groups, counted lgkmcnt(15) depth-3) and cuts the chain to
// fma -> exp2 -> add -> rcp:
//  * delayed insert: lane1's window newest tap is u_{k-2} (2-node slack);
//    u_{k-1} enters ONLY via post-reduce inject fma using the uniform rcp
//    output reg (no cross-lane hop on chain).
//  * w15 delivered via meta (b64 -> b128 upgrade, same 5-read count);
//    lane1's tap mismatch absorbed by a staged ZERO weight on its oldest tap.
//  * migration (dpp+cndmask) consumed 2 nodes later -> off-chain.
// Window mapping at node k: tap T_m = lane0 u_{k-16+m} / lane1 u_{k-9+m};
// weights: lane0 [w"0..w"7], lane1 [0, w"8..w"14]; meta (Bh, w"15) per node.

typedef float v4f __attribute__((ext_vector_type(4)));

constexpr int kNOut     = 64;
constexpr int kBatch    = 32768;
constexpr int kGStrideF = 48;                       // floats per 2-node group (192 B)
constexpr int kLdsFloats = (256 + 3) * kGStrideF;   // 256 groups + prefetch overrun pad
constexpr float kScale  = 2.8853900817779268f;      // 2*log2(e)

// quad_perm DPP through the builtin so the compiler handles hazard nops.
#define QPERM(X, CTRL) __int_as_float(__builtin_amdgcn_update_dpp(            \
    __float_as_int(X), __float_as_int(X), (CTRL), 0xF, 0xF, false))

// 5 ds_read for group S: per-lane weight halves of both nodes + meta b128
// (BhA, w15A, BhB, w15B; lane replicas 32B apart). Cursor a = base + 32*jl:
// lane0 meta at byte 128, lane1 replica at 160.
#define PREF(S) {                                                             \
    asm volatile(                                                             \
      "ds_read_b128 %0, %5 offset:0\n\t"                                      \
      "ds_read_b128 %1, %5 offset:16\n\t"                                     \
      "ds_read_b128 %2, %5 offset:64\n\t"                                     \
      "ds_read_b128 %3, %5 offset:80\n\t"                                     \
      "ds_read_b128 %4, %5 offset:128"                                        \
      : "=&v"(qa[S]), "=&v"(qb[S]), "=&v"(qc[S]), "=&v"(qd[S]), "=&v"(qm[S])  \
      : "v"(a));                                                              \
    a += kGStrideF * 4; }

// After PREF of group G+3, the 15 newer reads (groups G+1..G+3) may remain
// outstanding; in-order DS returns make lgkmcnt(15) == "set G landed".
#define WAITG(S)                                                              \
    asm volatile("s_waitcnt lgkmcnt(15)"                                      \
      : "+v"(qa[S]), "+v"(qb[S]), "+v"(qc[S]), "+v"(qd[S]), "+v"(qm[S]));

// One node. Taps A0..A7 hold lane-divergent window values (see header map).
// All 8 partial fmas + the pair reduce are OFF-chain (no tap contains
// u_{k-1}; lane1's A0 pad-read is a 7-node-old value x 0.0 weight).
// Chain: acc = fma(UIN, W15, s) -> exp2 -> add -> rcp -> UOUT.
// Migration recycles A0 as next node's newest tap: lane0 pulls partner's
// A1 (u_{k-8}); lane1 takes u_{k-1} (uniform reg).
#define NODE1(WLO, WHI, BH, W15, UIN, UOUT, A0,A1,A2,A3,A4,A5,A6,A7) {        \
    float p = fmaf((A0), (WLO).x, (BH));                                      \
    p = fmaf((A1), (WLO).y, p);                                               \
    p = fmaf((A2), (WLO).z, p);                                               \
    p = fmaf((A3), (WLO).w, p);                                               \
    p = fmaf((A4), (WHI).x, p);                                               \
    p = fmaf((A5), (WHI).y, p);                                               \
    p = fmaf((A6), (WHI).z, p);                                               \
    p = fmaf((A7), (WHI).w, p);                                               \
    float s_ = p + QPERM(p, 0xB1);          /* quad_perm:[1,0,3,2] */         \
    float mg = QPERM((A1), 0xB1);           /* partner's u_{k-8} */           \
    float acc = fmaf((UIN), (W15), s_);     /* chain starts here */           \
    float exv = __builtin_amdgcn_exp2f(acc);                                  \
    (UOUT) = __builtin_amdgcn_rcpf(exv + 1.0f);                               \
    (A0) = is_l1 ? (UIN) : mg; }

// 2-node group: prefetch group G+3, wait for group G, run both nodes.
// Tap names rotate-left by 1 per node (A0 recycled as the new newest).
#define GROUP(G, A0,A1,A2,A3,A4,A5,A6,A7) {                                   \
    PREF(((G) + 3) & 3)                                                       \
    WAITG((G) & 3)                                                            \
    NODE1(qa[(G)&3], qb[(G)&3], qm[(G)&3].x, qm[(G)&3].y, u0, u1,             \
          A0,A1,A2,A3,A4,A5,A6,A7)                                            \
    NODE1(qc[(G)&3], qd[(G)&3], qm[(G)&3].z, qm[(G)&3].w, u1, u0,             \
          A1,A2,A3,A4,A5,A6,A7,A0) }

__global__ __launch_bounds__(256) void neat_fwd(
    const float* __restrict__ x,      // [B, 16]
    const float* __restrict__ w,      // [512, 16]
    const float* __restrict__ bias,   // [512]
    const float* __restrict__ resp,   // [512]
    float* __restrict__ out)          // [B, 64]
{
    __shared__ alignas(16) float ldsw[kLdsFloats];
    __shared__ float rst[512];

    const int t  = threadIdx.x;       // 0..255 (4 waves)
    const int jl = t & 1;             // lane within pair
    const bool is_l1 = (jl == 1);

    // ---- Stage: raw resp first ----
    rst[t] = resp[t];
    rst[t + 256] = resp[t + 256];
    __syncthreads();

    // ---- Stage per node (each thread owns 2 whole nodes): ----
    // lane0 half  = [w"0..w"7], lane1 half = [0, w"8..w"14],
    // meta (Bh, w"15) with lane replicas; w" = -2*kScale*w*rho,
    // Bh = kScale*(b + sum_j w*rho)/2.
    const float4* __restrict__ w4 = reinterpret_cast<const float4*>(w);
    const float m2k = -2.0f * kScale;
    #pragma unroll
    for (int k = 0; k < 2; ++k) {
        int n = t + (k << 8);
        float4 a0 = w4[n*4+0], a1 = w4[n*4+1], a2 = w4[n*4+2], a3 = w4[n*4+3];
        float wv0=a0.x, wv1=a0.y, wv2=a0.z, wv3=a0.w;
        float wv4=a1.x, wv5=a1.y, wv6=a1.z, wv7=a1.w;
        float wv8=a2.x, wv9=a2.y, wv10=a2.z, wv11=a2.w;
        float wv12=a3.x, wv13=a3.y, wv14=a3.z, wv15=a3.w;
        float sum = 0.0f;
        float ws0,ws1,ws2,ws3,ws4,ws5,ws6,ws7,ws8,ws9,ws10,ws11,ws12,ws13,ws14,ws15;
        #define DO(J) { float rho = (n + J < 16) ? 1.0f : rst[n + J - 16];    \
                        float wr = wv##J * rho; sum += wr; ws##J = wr * m2k; }
        DO(0) DO(1) DO(2) DO(3) DO(4) DO(5) DO(6) DO(7)
        DO(8) DO(9) DO(10) DO(11) DO(12) DO(13) DO(14) DO(15)
        #undef DO
        int q = n >> 1, h = n & 1;
        float* gb = ldsw + q * kGStrideF;
        *reinterpret_cast<float4*>(gb + h*16 + 0)  = make_float4(ws0, ws1, ws2, ws3);
        *reinterpret_cast<float4*>(gb + h*16 + 4)  = make_float4(ws4, ws5, ws6, ws7);
        *reinterpret_cast<float4*>(gb + h*16 + 8)  = make_float4(0.0f, ws8, ws9, ws10);
        *reinterpret_cast<float4*>(gb + h*16 + 12) = make_float4(ws11, ws12, ws13, ws14);
        float Bh = (bias[n] + sum) * (kScale * 0.5f);
        gb[32 + h*2] = Bh;  gb[33 + h*2] = ws15;   // lane0 meta (byte 128)
        gb[40 + h*2] = Bh;  gb[41 + h*2] = ws15;   // lane1 replica (byte 160)
    }

    // ---- Per-thread window init (u-encoded inputs) ----
    // Node 0 taps: lane0 = enc(x0..x7), lane1 = enc(x7..x14); u_prev = enc(x15).
    const int e = blockIdx.x * 128 + (t >> 1);     // batch element
    const float4* __restrict__ x4p = reinterpret_cast<const float4*>(x);
    float4 X0 = x4p[e*4+0], X1 = x4p[e*4+1], X2 = x4p[e*4+2], X3 = x4p[e*4+3];
    float xx0 = fmaf(-0.5f, X0.x, 0.5f), xx1 = fmaf(-0.5f, X0.y, 0.5f);
    float xx2 = fmaf(-0.5f, X0.z, 0.5f), xx3 = fmaf(-0.5f, X0.w, 0.5f);
    float xx4 = fmaf(-0.5f, X1.x, 0.5f), xx5 = fmaf(-0.5f, X1.y, 0.5f);
    float xx6 = fmaf(-0.5f, X1.z, 0.5f), xx7 = fmaf(-0.5f, X1.w, 0.5f);
    float xx8 = fmaf(-0.5f, X2.x, 0.5f), xx9 = fmaf(-0.5f, X2.y, 0.5f);
    float xx10 = fmaf(-0.5f, X2.z, 0.5f), xx11 = fmaf(-0.5f, X2.w, 0.5f);
    float xx12 = fmaf(-0.5f, X3.x, 0.5f), xx13 = fmaf(-0.5f, X3.y, 0.5f);
    float xx14 = fmaf(-0.5f, X3.z, 0.5f), xx15 = fmaf(-0.5f, X3.w, 0.5f);
    float r0 = is_l1 ? xx7  : xx0;
    float r1 = is_l1 ? xx8  : xx1;
    float r2 = is_l1 ? xx9  : xx2;
    float r3 = is_l1 ? xx10 : xx3;
    float r4 = is_l1 ? xx11 : xx4;
    float r5 = is_l1 ? xx12 : xx5;
    float r6 = is_l1 ? xx13 : xx6;
    float r7 = is_l1 ? xx14 : xx7;
    float u0 = xx15;          // u_{-1} (uniform)
    float u1 = 0.0f;

    const float4* __restrict__ rr4 = reinterpret_cast<const float4*>(resp);
    float* __restrict__ op = out + (size_t)e * kNOut + jl * 8;

    __syncthreads();   // drains staging ds ops (compiler lgkmcnt(0))

    // DS byte cursor (+ lane's 32B weight-half offset folded in).
    unsigned int a = (unsigned int)(unsigned long long)(&ldsw[0])
                   + (unsigned int)(jl << 5);

    v4f qa[4], qb[4], qc[4], qd[4], qm[4];
    PREF(0) PREF(1) PREF(2)     // groups 0,1,2 in flight

    #pragma unroll 1
    for (int g = 0; g < 32; ++g) {
        // 16 nodes = 8 groups; tap names advance 2 per group (period 8).
        GROUP(0, r0,r1,r2,r3,r4,r5,r6,r7)
        GROUP(1, r2,r3,r4,r5,r6,r7,r0,r1)
        GROUP(2, r4,r5,r6,r7,r0,r1,r2,r3)
        GROUP(3, r6,r7,r0,r1,r2,r3,r4,r5)
        GROUP(4, r0,r1,r2,r3,r4,r5,r6,r7)
        GROUP(5, r2,r3,r4,r5,r6,r7,r0,r1)
        GROUP(6, r4,r5,r6,r7,r0,r1,r2,r3)
        GROUP(7, r6,r7,r0,r1,r2,r3,r4,r5)
        // After 16 nodes (K = 16(g+1)): lane0 r_c = u_{16g+c};
        // lane1 r_{c+1} = u_{16g+8+c}, and u_{16g+15} = u0.
        if (g >= 28) {
            int m = g - 28;
            const float4 ra = rr4[112 + 4 * m + 2 * jl];
            const float4 rb = rr4[112 + 4 * m + 2 * jl + 1];
            float o0 = is_l1 ? r1 : r0;
            float o1 = is_l1 ? r2 : r1;
            float o2 = is_l1 ? r3 : r2;
            float o3 = is_l1 ? r4 : r3;
            float o4 = is_l1 ? r5 : r4;
            float o5 = is_l1 ? r6 : r5;
            float o6 = is_l1 ? r7 : r6;
            float o7 = is_l1 ? u0 : r7;
            float4 q0_ = make_float4(fmaf(-2.0f, o0, 1.0f) * ra.x,
                                     fmaf(-2.0f, o1, 1.0f) * ra.y,
                                     fmaf(-2.0f, o2, 1.0f) * ra.z,
                                     fmaf(-2.0f, o3, 1.0f) * ra.w);
            float4 q1_ = make_float4(fmaf(-2.0f, o4, 1.0f) * rb.x,
                                     fmaf(-2.0f, o5, 1.0f) * rb.y,
                                     fmaf(-2.0f, o6, 1.0f) * rb.z,
                                     fmaf(-2.0f, o7, 1.0f) * rb.w);
            *reinterpret_cast<float4*>(op + 16 * m)     = q0_;
            *reinterpret_cast<float4*>(op + 16 * m + 4) = q1_;
        }
    }

    // Drain overrun prefetches (pad groups 256..258).
    asm volatile("s_waitcnt lgkmcnt(0)" ::: "memory");
}

extern "C" void kernel_launch(void* const* d_in, const int* in_sizes, int n_in,
                              void* d_out, int out_size, void* d_ws, size_t ws_size,
                              hipStream_t stream) {
    const float* x    = (const float*)d_in[0];
    const float* w    = (const float*)d_in[1];
    const float* bias = (const float*)d_in[2];
    const float* resp = (const float*)d_in[3];
    float* out = (float*)d_out;
    // in_sizes[4] (src_idx) encodes the fixed windowed topology; hardcoded above.
    dim3 block(256);
    dim3 grid(kBatch / 128);   // 256 blocks -> 1/CU, 4 waves/CU = 1 per SIMD
    hipLaunchKernelGGL(neat_fwd, grid, block, 0, stream, x, w, bias, resp, out);
}